// Round 2
// baseline (238.345 us; speedup 1.0000x reference)
//
#include <hip/hip_runtime.h>
#include <hip/hip_fp16.h>

// Problem constants (from reference)
constexpr int B        = 2;
constexpr int N_IN     = 262144;
constexpr int D        = 32;
constexpr int N_OUT    = 65536;
constexpr int K        = 4;
constexpr int NK       = 9;
constexpr int P        = B * N_OUT * K;   // 524288 output points
constexpr int PK_BITS  = 18;              // N_OUT*K = 2^18 points per batch
constexpr size_t XTOT  = (size_t)B * N_IN * D;  // 16,777,216 feature elements

typedef _Float16 half4v __attribute__((ext_vector_type(4)));
typedef _Float16 half8v __attribute__((ext_vector_type(8)));

// ---------------- pre-pass: fp32 feature table -> fp16 table in d_ws --------
__global__ __launch_bounds__(256) void cvt_fp16_kernel(
    const float* __restrict__ x, _Float16* __restrict__ xh)
{
    const size_t i = (size_t)(blockIdx.x * 256 + threadIdx.x) * 8;
    const float4 a = *reinterpret_cast<const float4*>(x + i);
    const float4 b = *reinterpret_cast<const float4*>(x + i + 4);
    half8v h;
    h[0] = (_Float16)a.x; h[1] = (_Float16)a.y;
    h[2] = (_Float16)a.z; h[3] = (_Float16)a.w;
    h[4] = (_Float16)b.x; h[5] = (_Float16)b.y;
    h[6] = (_Float16)b.z; h[7] = (_Float16)b.w;
    *reinterpret_cast<half8v*>(xh + i) = h;
}

// ---------------- main kernel, fp16 feature gathers --------------------------
// 8 lanes per point, each lane handles 4 channels.
__global__ __launch_bounds__(256) void projection_kernel_h(
    const _Float16* __restrict__ xh,      // (B, N_IN, D) fp16
    const float* __restrict__ coords_in,  // (2, B, N_IN)
    const float* __restrict__ coords_out, // (2, P)
    const float* __restrict__ sigma,      // (D,)
    const int*   __restrict__ nidx,       // (P, NK)
    float*       __restrict__ out)        // (P, D)
{
    const int tid   = blockIdx.x * 256 + threadIdx.x;
    const int point = tid >> 3;
    const int q     = tid & 7;

    const int b     = point >> PK_BITS;
    const int cbase = b * N_IN;

    const float cox = coords_out[point];
    const float coy = coords_out[P + point];

    const float4 sg = *reinterpret_cast<const float4*>(sigma + q * 4);
    const float s0 = 1.0f / (2.0f * sg.x * sg.x);
    const float s1 = 1.0f / (2.0f * sg.y * sg.y);
    const float s2 = 1.0f / (2.0f * sg.z * sg.z);
    const float s3 = 1.0f / (2.0f * sg.w * sg.w);

    float4 num = make_float4(0.f, 0.f, 0.f, 0.f);
    float4 den = make_float4(0.f, 0.f, 0.f, 0.f);

    const int* __restrict__ ip = nidx + (size_t)point * NK;

    #pragma unroll
    for (int nk = 0; nk < NK; ++nk) {
        const int idx = ip[nk];
        const float cx = coords_in[cbase + idx];
        const float cy = coords_in[B * N_IN + cbase + idx];
        const float dx = cox - cx;
        const float dy = coy - cy;
        const float d2 = dx * dx + dy * dy;

        // 8 lanes x 8 B = contiguous 64 B segment per neighbor row
        const half4v f = *reinterpret_cast<const half4v*>(
            xh + (size_t)(cbase + idx) * D + q * 4);

        const float w0 = __expf(-d2 * s0);
        const float w1 = __expf(-d2 * s1);
        const float w2 = __expf(-d2 * s2);
        const float w3 = __expf(-d2 * s3);

        num.x += w0 * (float)f[0];  den.x += w0;
        num.y += w1 * (float)f[1];  den.y += w1;
        num.z += w2 * (float)f[2];  den.z += w2;
        num.w += w3 * (float)f[3];  den.w += w3;
    }

    float4 o;
    o.x = num.x / (den.x + 1e-9f);
    o.y = num.y / (den.y + 1e-9f);
    o.z = num.z / (den.z + 1e-9f);
    o.w = num.w / (den.w + 1e-9f);

    *reinterpret_cast<float4*>(out + (size_t)point * D + q * 4) = o;
}

// ---------------- fallback: proven fp32 path (if ws too small) ---------------
__global__ __launch_bounds__(256) void projection_kernel_f32(
    const float* __restrict__ x,
    const float* __restrict__ coords_in,
    const float* __restrict__ coords_out,
    const float* __restrict__ sigma,
    const int*   __restrict__ nidx,
    float*       __restrict__ out)
{
    const int tid   = blockIdx.x * 256 + threadIdx.x;
    const int point = tid >> 3;
    const int q     = tid & 7;
    const int b     = point >> PK_BITS;
    const int cbase = b * N_IN;

    const float cox = coords_out[point];
    const float coy = coords_out[P + point];

    const float4 sg = *reinterpret_cast<const float4*>(sigma + q * 4);
    const float s0 = 1.0f / (2.0f * sg.x * sg.x);
    const float s1 = 1.0f / (2.0f * sg.y * sg.y);
    const float s2 = 1.0f / (2.0f * sg.z * sg.z);
    const float s3 = 1.0f / (2.0f * sg.w * sg.w);

    float4 num = make_float4(0.f, 0.f, 0.f, 0.f);
    float4 den = make_float4(0.f, 0.f, 0.f, 0.f);
    const int* __restrict__ ip = nidx + (size_t)point * NK;

    #pragma unroll
    for (int nk = 0; nk < NK; ++nk) {
        const int idx = ip[nk];
        const float cx = coords_in[cbase + idx];
        const float cy = coords_in[B * N_IN + cbase + idx];
        const float dx = cox - cx;
        const float dy = coy - cy;
        const float d2 = dx * dx + dy * dy;
        const float4 f = *reinterpret_cast<const float4*>(
            x + (size_t)(cbase + idx) * D + q * 4);
        const float w0 = __expf(-d2 * s0);
        const float w1 = __expf(-d2 * s1);
        const float w2 = __expf(-d2 * s2);
        const float w3 = __expf(-d2 * s3);
        num.x += w0 * f.x;  den.x += w0;
        num.y += w1 * f.y;  den.y += w1;
        num.z += w2 * f.z;  den.z += w2;
        num.w += w3 * f.w;  den.w += w3;
    }

    float4 o;
    o.x = num.x / (den.x + 1e-9f);
    o.y = num.y / (den.y + 1e-9f);
    o.z = num.z / (den.z + 1e-9f);
    o.w = num.w / (den.w + 1e-9f);
    *reinterpret_cast<float4*>(out + (size_t)point * D + q * 4) = o;
}

extern "C" void kernel_launch(void* const* d_in, const int* in_sizes, int n_in,
                              void* d_out, int out_size, void* d_ws, size_t ws_size,
                              hipStream_t stream) {
    const float* x      = (const float*)d_in[0];
    const float* cin    = (const float*)d_in[1];
    const float* cout_  = (const float*)d_in[2];
    const float* sigma  = (const float*)d_in[3];
    const int*   nidx   = (const int*)  d_in[4];
    float*       outp   = (float*)d_out;

    const int block = 256;
    const int grid_main = (P * 8) / block;   // 16384

    if (ws_size >= XTOT * sizeof(_Float16)) {
        _Float16* xh = (_Float16*)d_ws;
        const int grid_cvt = (int)(XTOT / 8 / block);   // 8192
        cvt_fp16_kernel<<<grid_cvt, block, 0, stream>>>(x, xh);
        projection_kernel_h<<<grid_main, block, 0, stream>>>(
            xh, cin, cout_, sigma, nidx, outp);
    } else {
        projection_kernel_f32<<<grid_main, block, 0, stream>>>(
            x, cin, cout_, sigma, nidx, outp);
    }
}